// Round 1
// baseline (504.583 us; speedup 1.0000x reference)
//
#include <hip/hip_runtime.h>
#include <stdint.h>

typedef unsigned long long u64;

#define B_    32
#define CIN   256
#define COUT  256
#define H_    56
#define W_    56
#define HW    3136            // H_*W_
#define NPOS  100352          // B_*HW
#define NROW  1792            // B_*H_
#define NOUT  25690112        // B_*COUT*HW

// ---- workspace layout (bytes) ----
// 0        : wbits  u64[256*36]            73728
// 73728    : alpha  float[256]             1024
// 74752    : scale  float[256]             1024
// 75776    : shift  float[256]             1024
// 76800    : xbits  u64[NPOS*4]            3211264
// 3288064  : Sarr   short[NOUT]            51380224
// total ~54.7 MB

// ---------------- Kernel W: weight prep (mean-center, clip, alpha, bitpack) ----------------
__global__ __launch_bounds__(256) void kw_weights(
    const float* __restrict__ wgt,   // [O=256, I=256, 3, 3]
    u64* __restrict__ wbits,         // [O][9 taps][4 words]
    float* __restrict__ alpha)
{
    const int o = blockIdx.x;
    const int i = threadIdx.x;       // input channel
    __shared__ float red[256];

    float w9[9];
#pragma unroll
    for (int t = 0; t < 9; ++t) w9[t] = wgt[(o * 256 + i) * 9 + t];

    // per-tap mean over input channels
    float m[9];
#pragma unroll
    for (int t = 0; t < 9; ++t) {
        red[i] = w9[t];
        __syncthreads();
        for (int s = 128; s > 0; s >>= 1) {
            if (i < s) red[i] += red[i + s];
            __syncthreads();
        }
        m[t] = red[0] * (1.0f / 256.0f);
        __syncthreads();
    }

    float wc[9];
    float asum = 0.0f;
#pragma unroll
    for (int t = 0; t < 9; ++t) {
        float v = w9[t] - m[t];
        v = fminf(fmaxf(v, -1.0f), 1.0f);
        wc[t] = v;
        asum += fabsf(v);
    }
    red[i] = asum;
    __syncthreads();
    for (int s = 128; s > 0; s >>= 1) {
        if (i < s) red[i] += red[i + s];
        __syncthreads();
    }
    if (i == 0) alpha[o] = red[0] * (1.0f / 2304.0f);

    const int wave = i >> 6, lane = i & 63;
#pragma unroll
    for (int t = 0; t < 9; ++t) {
        u64 b = __ballot(wc[t] > 0.0f);   // bit=1 <-> +1, bit=0 <-> -1
        if (lane == 0) wbits[o * 36 + t * 4 + wave] = b;
    }
}

// ---------------- Kernel P: pack sign(x) bits, 4 u64 per (b,h,w) ----------------
__global__ __launch_bounds__(256) void kp_pack(
    const float* __restrict__ x,     // [B, C, H, W]
    u64* __restrict__ xbits)         // [NPOS][4]
{
    const int p = blockIdx.x * 256 + threadIdx.x;   // 392*256 == NPOS exactly
    const int b = p / HW;
    const int hw = p - b * HW;
    const float* xp = x + (size_t)b * CIN * HW + hw;
    for (int j = 0; j < 4; ++j) {
        u64 bits = 0;
#pragma unroll
        for (int k = 0; k < 64; ++k) {
            float v = xp[(size_t)(j * 64 + k) * HW];
            bits |= (u64)(v > 0.0f) << k;
        }
        xbits[(size_t)p * 4 + j] = bits;
    }
}

// ---------------- Kernel C: XNOR-popcount conv -> S (int16) ----------------
__global__ __launch_bounds__(256) void kc_conv(
    const u64* __restrict__ xbits,
    const u64* __restrict__ wbits,
    short* __restrict__ Sarr)
{
    const int blk = blockIdx.x;        // 0..NROW-1 : one (b,h) row per block
    const int b = blk / H_;
    const int h = blk - b * H_;

    __shared__ u64 tile[3 * W_ * 4];   // rows h-1..h+1 (clamped), [r][w][j]
    for (int idx = threadIdx.x; idx < 3 * W_ * 4; idx += 256) {
        int r = idx / (W_ * 4);
        int rem = idx - r * (W_ * 4);
        int hr = h - 1 + r;
        hr = min(max(hr, 0), H_ - 1);
        tile[idx] = xbits[((size_t)b * HW + (size_t)hr * W_) * 4 + rem];
    }
    __syncthreads();

    const int lane = threadIdx.x & 63;
    const int w = lane;                 // active when < 56
    const bool act = (w < W_);
    const int wcl = act ? w : (W_ - 1);

    // tap validity mask (padding = zero contribution)
    int vm = 0;
#pragma unroll
    for (int t = 0; t < 9; ++t) {
        int kh = t / 3, kw = t % 3;
        bool v = (h + kh - 1 >= 0) && (h + kh - 1 < H_) &&
                 (w + kw - 1 >= 0) && (w + kw - 1 < W_);
        if (v) vm |= (1 << t);
    }

    // load this lane's 9-tap x words into registers
    u64 xw[36];
#pragma unroll
    for (int t = 0; t < 9; ++t) {
        int kh = t / 3, kw = t % 3;
        int col = min(max(wcl + kw - 1, 0), W_ - 1);
#pragma unroll
        for (int j = 0; j < 4; ++j)
            xw[t * 4 + j] = tile[(kh * W_ + col) * 4 + j];
    }

    // force wave-uniform o so weight loads scalarize (s_load from K$)
    const int obase = __builtin_amdgcn_readfirstlane((threadIdx.x >> 6) << 6);

    for (int i = 0; i < 64; ++i) {
        const int o = obase + i;
        const u64* wb = wbits + o * 36;
        int S = 0;
#pragma unroll
        for (int t = 0; t < 9; ++t) {
            int pc = __popcll(xw[t * 4 + 0] ^ wb[t * 4 + 0])
                   + __popcll(xw[t * 4 + 1] ^ wb[t * 4 + 1])
                   + __popcll(xw[t * 4 + 2] ^ wb[t * 4 + 2])
                   + __popcll(xw[t * 4 + 3] ^ wb[t * 4 + 3]);
            S += ((vm >> t) & 1) ? (256 - 2 * pc) : 0;
        }
        if (act)
            Sarr[((size_t)b * COUT + o) * HW + h * W_ + w] = (short)S;
    }
}

// ---------------- Kernel R: exact per-channel stats -> scale/shift ----------------
__global__ __launch_bounds__(256) void kr_stats(
    const short* __restrict__ Sarr,
    const float* __restrict__ alpha,
    const float* __restrict__ gamma,
    const float* __restrict__ beta,
    float* __restrict__ scale,
    float* __restrict__ shift)
{
    const int o = blockIdx.x;
    const int tid = threadIdx.x;

    int s32 = 0;
    long long q64 = 0;
    // per-channel data: 32 chunks of 3136 shorts; iterate in int4 (8 shorts)
    for (int f8 = tid; f8 < NPOS / 8; f8 += 256) {
        int b = f8 / (HW / 8);
        int rem = f8 - b * (HW / 8);
        const int4 v = *reinterpret_cast<const int4*>(
            Sarr + ((size_t)b * COUT + o) * HW + (size_t)rem * 8);
        union { int4 vv; short s[8]; } u;
        u.vv = v;
        int qs = 0;
#pragma unroll
        for (int k = 0; k < 8; ++k) {
            int sv = u.s[k];
            s32 += sv;
            qs += sv * sv;
        }
        q64 += (long long)qs;
    }

    __shared__ long long rs[256];
    __shared__ long long rq[256];
    rs[tid] = s32;
    rq[tid] = q64;
    __syncthreads();
    for (int st = 128; st > 0; st >>= 1) {
        if (tid < st) { rs[tid] += rs[tid + st]; rq[tid] += rq[tid + st]; }
        __syncthreads();
    }
    if (tid == 0) {
        const double N = (double)NPOS;
        double meanS = (double)rs[0] / N;
        double varS = (double)rq[0] / N - meanS * meanS;
        double a = (double)alpha[o];
        double rstd = 1.0 / sqrt(a * a * varS + 1e-5);
        double g = (double)gamma[o];
        scale[o] = (float)(g * a * rstd);
        shift[o] = (float)((double)beta[o] - g * a * meanS * rstd);
        // note: conv bias cancels exactly in training-mode BN
    }
}

// ---------------- Kernel B: apply BN affine + ReLU ----------------
__global__ __launch_bounds__(256) void kb_apply(
    const short* __restrict__ Sarr,
    const float* __restrict__ scale,
    const float* __restrict__ shift,
    float* __restrict__ out)
{
    const size_t i8 = ((size_t)blockIdx.x * 256 + threadIdx.x) * 8;
    if (i8 >= (size_t)NOUT) return;
    const int ch = (int)((i8 / HW) & (COUT - 1));
    const float sc = scale[ch];
    const float sh = shift[ch];

    union { int4 vv; short s[8]; } u;
    u.vv = *reinterpret_cast<const int4*>(Sarr + i8);

    float4 o0, o1;
    o0.x = fmaxf(0.0f, fmaf((float)u.s[0], sc, sh));
    o0.y = fmaxf(0.0f, fmaf((float)u.s[1], sc, sh));
    o0.z = fmaxf(0.0f, fmaf((float)u.s[2], sc, sh));
    o0.w = fmaxf(0.0f, fmaf((float)u.s[3], sc, sh));
    o1.x = fmaxf(0.0f, fmaf((float)u.s[4], sc, sh));
    o1.y = fmaxf(0.0f, fmaf((float)u.s[5], sc, sh));
    o1.z = fmaxf(0.0f, fmaf((float)u.s[6], sc, sh));
    o1.w = fmaxf(0.0f, fmaf((float)u.s[7], sc, sh));

    float4* op = reinterpret_cast<float4*>(out + i8);
    op[0] = o0;
    op[1] = o1;
}

extern "C" void kernel_launch(void* const* d_in, const int* in_sizes, int n_in,
                              void* d_out, int out_size, void* d_ws, size_t ws_size,
                              hipStream_t stream) {
    const float* x     = (const float*)d_in[0];   // [32,256,56,56]
    const float* wgt   = (const float*)d_in[1];   // [256,256,3,3]
    // d_in[2] = bias: cancels exactly in BN, unused
    const float* gamma = (const float*)d_in[3];
    const float* beta  = (const float*)d_in[4];
    float* out = (float*)d_out;

    char* ws = (char*)d_ws;
    u64*   wbits = (u64*)(ws + 0);
    float* alpha = (float*)(ws + 73728);
    float* scale = (float*)(ws + 74752);
    float* shift = (float*)(ws + 75776);
    u64*   xbits = (u64*)(ws + 76800);
    short* Sarr  = (short*)(ws + 3288064);

    kw_weights<<<256, 256, 0, stream>>>(wgt, wbits, alpha);
    kp_pack<<<NPOS / 256, 256, 0, stream>>>(x, xbits);
    kc_conv<<<NROW, 256, 0, stream>>>(xbits, wbits, Sarr);
    kr_stats<<<COUT, 256, 0, stream>>>(Sarr, alpha, gamma, beta, scale, shift);
    kb_apply<<<NOUT / 8 / 256, 256, 0, stream>>>(Sarr, scale, shift, out);
}

// Round 2
// 362.978 us; speedup vs baseline: 1.3901x; 1.3901x over previous
//
#include <hip/hip_runtime.h>
#include <stdint.h>

typedef unsigned long long u64;
typedef unsigned int u32;

#define B_    32
#define CIN   256
#define COUT  256
#define H_    56
#define W_    56
#define HW    3136            // H_*W_
#define NPOS  100352          // B_*HW
#define NROW  1792            // B_*H_

// ---- workspace layout (bytes) ----
// 0       : wbits u64[256*36]        73728
// 73728   : alpha f32[256]           1024
// 74752   : scale f32[256]           1024
// 75776   : shift f32[256]           1024
// 76800   : ssum  i32[256]           1024
// 77824   : qsum  u64[256]           2048
// 79872   : xbits u64[NPOS*4]        3211264   (ends 3291136)
// 3291136 : S     s16[NPOS*256] NHWC 51380224  (ends ~54.7 MB)

// ---------------- Kernel W: weight prep + zero stats accumulators ----------------
__global__ __launch_bounds__(256) void kw_weights(
    const float* __restrict__ wgt,   // [O=256, I=256, 3, 3]
    u64* __restrict__ wbits,         // [O][9 taps][4 words]
    float* __restrict__ alpha,
    int* __restrict__ ssum,
    unsigned long long* __restrict__ qsum)
{
    const int o = blockIdx.x;
    const int i = threadIdx.x;       // input channel
    __shared__ float red[256];

    if (i == 0) { ssum[o] = 0; qsum[o] = 0ULL; }

    float w9[9];
#pragma unroll
    for (int t = 0; t < 9; ++t) w9[t] = wgt[(o * 256 + i) * 9 + t];

    float m[9];
#pragma unroll
    for (int t = 0; t < 9; ++t) {
        red[i] = w9[t];
        __syncthreads();
        for (int s = 128; s > 0; s >>= 1) {
            if (i < s) red[i] += red[i + s];
            __syncthreads();
        }
        m[t] = red[0] * (1.0f / 256.0f);
        __syncthreads();
    }

    float wc[9];
    float asum = 0.0f;
#pragma unroll
    for (int t = 0; t < 9; ++t) {
        float v = w9[t] - m[t];
        v = fminf(fmaxf(v, -1.0f), 1.0f);
        wc[t] = v;
        asum += fabsf(v);
    }
    red[i] = asum;
    __syncthreads();
    for (int s = 128; s > 0; s >>= 1) {
        if (i < s) red[i] += red[i + s];
        __syncthreads();
    }
    if (i == 0) alpha[o] = red[0] * (1.0f / 2304.0f);

    const int wave = i >> 6, lane = i & 63;
#pragma unroll
    for (int t = 0; t < 9; ++t) {
        u64 bb = __ballot(wc[t] > 0.0f);   // bit=1 <-> +1
        if (lane == 0) wbits[o * 36 + t * 4 + wave] = bb;
    }
}

// ---------------- Kernel P: pack sign(x) bits ----------------
__global__ __launch_bounds__(256) void kp_pack(
    const float* __restrict__ x,     // [B, C, H, W]
    u64* __restrict__ xbits)         // [NPOS][4]
{
    const int p = blockIdx.x * 256 + threadIdx.x;   // 392*256 == NPOS
    const int j = blockIdx.y;                        // channel chunk
    const int b = p / HW;
    const int hw = p - b * HW;
    const float* xp = x + (size_t)b * CIN * HW + (size_t)j * 64 * HW + hw;
    u64 bits = 0;
#pragma unroll
    for (int k = 0; k < 64; ++k)
        bits |= (u64)(xp[(size_t)k * HW] > 0.0f) << k;
    xbits[(size_t)p * 4 + j] = bits;
}

// ---------------- conv row processor (lanes = o, uniform window) ----------------
template<int R0, int R1>
__device__ __forceinline__ void run_row(
    const u64* __restrict__ tile,    // [3][56][4]
    const u64 wr[36],                // this lane's weights [tap][j]
    short* __restrict__ srow,        // S + pos_base*256 + o
    int& s_acc, int& q_acc)
{
    constexpr int NR = R1 - R0 + 1;

    // ---- w = 0 : kw in {1,2} ----
    {
        int acc = 0;
#pragma unroll
        for (int kh = R0; kh <= R1; ++kh)
#pragma unroll
            for (int kw = 1; kw <= 2; ++kw)
#pragma unroll
                for (int j = 0; j < 4; ++j)
                    acc += (int)__popcll(tile[(kh * 56 + (kw - 1)) * 4 + j] ^ wr[(kh * 3 + kw) * 4 + j]);
        int S = NR * 2 * 256 - 2 * acc;
        srow[0] = (short)S; s_acc += S; q_acc += S * S;
    }

    // ring: slot(col) = col % 3; preload cols 0,1
    u64 xc[3][3][4];
#pragma unroll
    for (int kh = R0; kh <= R1; ++kh)
#pragma unroll
        for (int j = 0; j < 4; ++j) {
            xc[0][kh][j] = tile[(kh * 56 + 0) * 4 + j];
            xc[1][kh][j] = tile[(kh * 56 + 1) * 4 + j];
        }

    for (int wb = 1; wb <= 52; wb += 3) {
#pragma unroll
        for (int u = 0; u < 3; ++u) {
            const int w = wb + u;                 // 1..54, w % 3 == (1+u) % 3
            // load col w+1 into slot (u+2)%3
#pragma unroll
            for (int kh = R0; kh <= R1; ++kh)
#pragma unroll
                for (int j = 0; j < 4; ++j)
                    xc[(u + 2) % 3][kh][j] = tile[(kh * 56 + (w + 1)) * 4 + j];
            int acc = 0;
#pragma unroll
            for (int kh = R0; kh <= R1; ++kh)
#pragma unroll
                for (int kw = 0; kw < 3; ++kw)
#pragma unroll
                    for (int j = 0; j < 4; ++j)
                        acc += (int)__popcll(xc[(u + kw) % 3][kh][j] ^ wr[(kh * 3 + kw) * 4 + j]);
            int S = NR * 3 * 256 - 2 * acc;
            srow[w * 256] = (short)S; s_acc += S; q_acc += S * S;
        }
    }

    // ---- w = 55 : kw in {0,1}; cols 54,55 are in slots 0,1 ----
    {
        int acc = 0;
#pragma unroll
        for (int kh = R0; kh <= R1; ++kh)
#pragma unroll
            for (int kw = 0; kw <= 1; ++kw)
#pragma unroll
                for (int j = 0; j < 4; ++j)
                    acc += (int)__popcll(xc[(54 + kw) % 3][kh][j] ^ wr[(kh * 3 + kw) * 4 + j]);
        int S = NR * 2 * 256 - 2 * acc;
        srow[55 * 256] = (short)S; s_acc += S; q_acc += S * S;
    }
}

// ---------------- Kernel C: XNOR-popcount conv -> S (NHWC int16) + fused stats ----------------
__global__ __launch_bounds__(256) void kc_conv(
    const u64* __restrict__ xbits,
    const u64* __restrict__ wbits,
    short* __restrict__ S,           // [NPOS][256]
    int* __restrict__ ssum,
    unsigned long long* __restrict__ qsum)
{
    const int blk = blockIdx.x;        // (b,h)
    const int b = blk / H_;
    const int h = blk - b * H_;
    const int o = threadIdx.x;         // lane = consecutive o

    __shared__ u64 tile[3 * W_ * 4];   // rows h-1..h+1 (clamped), [r][w][j]
    for (int idx = threadIdx.x; idx < 3 * W_ * 4; idx += 256) {
        int r = idx / (W_ * 4);
        int rem = idx - r * (W_ * 4);
        int hr = min(max(h - 1 + r, 0), H_ - 1);
        tile[idx] = xbits[((size_t)(b * HW + hr * W_)) * 4 + rem];
    }

    // this lane's weights: 36 u64, register-resident
    u64 wr[36];
    const ulonglong2* wp = (const ulonglong2*)(wbits + (size_t)o * 36);
#pragma unroll
    for (int i = 0; i < 18; ++i) { ulonglong2 v = wp[i]; wr[2 * i] = v.x; wr[2 * i + 1] = v.y; }

    __syncthreads();

    short* srow = S + ((size_t)(b * HW + h * W_)) * 256 + o;
    int s_acc = 0, q_acc = 0;
    if (h == 0)        run_row<1, 2>(tile, wr, srow, s_acc, q_acc);
    else if (h == 55)  run_row<0, 1>(tile, wr, srow, s_acc, q_acc);
    else               run_row<0, 2>(tile, wr, srow, s_acc, q_acc);

    atomicAdd(&ssum[o], s_acc);
    atomicAdd(&qsum[o], (unsigned long long)(long long)q_acc);
}

// ---------------- Kernel F: finalize BN scale/shift ----------------
__global__ void kf_final(
    const int* __restrict__ ssum,
    const unsigned long long* __restrict__ qsum,
    const float* __restrict__ alpha,
    const float* __restrict__ gamma,
    const float* __restrict__ beta,
    float* __restrict__ scale,
    float* __restrict__ shift)
{
    const int o = threadIdx.x;
    const double N = (double)NPOS;
    double meanS = (double)ssum[o] / N;
    double varS = (double)qsum[o] / N - meanS * meanS;
    double a = (double)alpha[o];
    double rstd = 1.0 / sqrt(a * a * varS + 1e-5);
    double g = (double)gamma[o];
    scale[o] = (float)(g * a * rstd);
    shift[o] = (float)((double)beta[o] - g * a * meanS * rstd);
    // conv bias cancels exactly in training-mode BN
}

// ---------------- Kernel B: NHWC S -> NCHW out, BN affine + ReLU ----------------
__global__ __launch_bounds__(256) void kb_apply(
    const short* __restrict__ S,
    const float* __restrict__ scale,
    const float* __restrict__ shift,
    float* __restrict__ out)
{
    const int blk = blockIdx.x;        // (b,h)
    const int b = blk / H_;
    const int h = blk - b * H_;
    const int tid = threadIdx.x;

    __shared__ short lds[W_ * 258];    // [p][c], padded row stride 258 shorts (129 dwords)

    // coalesced copy in: row block is 56*256 shorts contiguous
    const u32* Sw = (const u32*)(S + ((size_t)(b * HW + h * W_)) * 256);
    for (int k = tid; k < W_ * 128; k += 256) {
        int p = k >> 7, cp = k & 127;
        u32 v = Sw[k];
        *(u32*)&lds[p * 258 + cp * 2] = v;
    }
    __syncthreads();

    const int p = tid & 63;            // position within row
    const int cq = tid >> 6;           // channel sub-group
    if (p < W_) {
        for (int it = 0; it < 64; ++it) {
            int c = it * 4 + cq;       // wave-uniform channel
            float sc = scale[c], sh = shift[c];
            float v = fmaf((float)lds[p * 258 + c], sc, sh);
            out[((size_t)(b * COUT + c)) * HW + h * W_ + p] = fmaxf(v, 0.0f);
        }
    }
}

extern "C" void kernel_launch(void* const* d_in, const int* in_sizes, int n_in,
                              void* d_out, int out_size, void* d_ws, size_t ws_size,
                              hipStream_t stream) {
    const float* x     = (const float*)d_in[0];   // [32,256,56,56]
    const float* wgt   = (const float*)d_in[1];   // [256,256,3,3]
    // d_in[2] = bias: cancels exactly in BN, unused
    const float* gamma = (const float*)d_in[3];
    const float* beta  = (const float*)d_in[4];
    float* out = (float*)d_out;

    char* ws = (char*)d_ws;
    u64*   wbits = (u64*)(ws + 0);
    float* alpha = (float*)(ws + 73728);
    float* scale = (float*)(ws + 74752);
    float* shift = (float*)(ws + 75776);
    int*   ssum  = (int*)(ws + 76800);
    unsigned long long* qsum = (unsigned long long*)(ws + 77824);
    u64*   xbits = (u64*)(ws + 79872);
    short* Sarr  = (short*)(ws + 3291136);

    kw_weights<<<256, 256, 0, stream>>>(wgt, wbits, alpha, ssum, qsum);
    kp_pack<<<dim3(NPOS / 256, 4), 256, 0, stream>>>(x, xbits);
    kc_conv<<<NROW, 256, 0, stream>>>(xbits, wbits, Sarr, ssum, qsum);
    kf_final<<<1, 256, 0, stream>>>(ssum, qsum, alpha, gamma, beta, scale, shift);
    kb_apply<<<NROW, 256, 0, stream>>>(Sarr, scale, shift, out);
}

// Round 3
// 350.844 us; speedup vs baseline: 1.4382x; 1.0346x over previous
//
#include <hip/hip_runtime.h>
#include <stdint.h>

typedef unsigned long long u64;
typedef unsigned int u32;

#define B_    32
#define CIN   256
#define COUT  256
#define H_    56
#define W_    56
#define HW    3136            // H_*W_
#define NPOS  100352          // B_*HW
#define NROW  1792            // B_*H_
#define NPACKBLK 1568         // (NPOS/256)*4

// ---- workspace layout (bytes) ----
// 0       : wbits u64[256*36]        73728
// 73728   : alpha f32[256]           1024
// 74752   : ssum  i32[256]           1024
// 75776   : qsum  u64[256]           2048
// 79872   : xbits u64[NPOS*4]        3211264   (ends 3291136)
// 3291136 : S     s16[NPOS*256] NHWC 51380224

// ---------------- Kernel 1: prep (x bitpack ∪ weight prep), grid-partitioned ----------------
__global__ __launch_bounds__(256) void k_prep(
    const float* __restrict__ x,     // [B, C, H, W]
    const float* __restrict__ wgt,   // [O=256, I=256, 3, 3]
    u64* __restrict__ xbits,         // [NPOS][4]
    u64* __restrict__ wbits,         // [O][9 taps][4 words]
    float* __restrict__ alpha,
    int* __restrict__ ssum,
    unsigned long long* __restrict__ qsum)
{
    const int tid = threadIdx.x;

    if (blockIdx.x < NPACKBLK) {
        // ---- pack sign(x) ----
        const int j = blockIdx.x / 392;                  // channel chunk
        const int p = (blockIdx.x - j * 392) * 256 + tid;
        const int b = p / HW;
        const int hw = p - b * HW;
        const float* xp = x + (size_t)b * CIN * HW + (size_t)j * 64 * HW + hw;
        u64 bits = 0;
#pragma unroll
        for (int k = 0; k < 64; ++k)
            bits |= (u64)(xp[(size_t)k * HW] > 0.0f) << k;
        xbits[(size_t)p * 4 + j] = bits;
        return;
    }

    // ---- weight prep: mean-center, clip, alpha, bitpack; zero stats ----
    const int o = blockIdx.x - NPACKBLK;
    const int i = tid;                 // input channel
    const int wave = i >> 6, lane = i & 63;
    __shared__ float sred[4][12];

    if (i == 0) { ssum[o] = 0; qsum[o] = 0ULL; }

    float w9[9];
#pragma unroll
    for (int t = 0; t < 9; ++t) w9[t] = wgt[(o * 256 + i) * 9 + t];

    float m[9];
#pragma unroll
    for (int t = 0; t < 9; ++t) m[t] = w9[t];
#pragma unroll
    for (int s = 1; s < 64; s <<= 1)
#pragma unroll
        for (int t = 0; t < 9; ++t) m[t] += __shfl_xor(m[t], s, 64);
    if (lane == 0) {
#pragma unroll
        for (int t = 0; t < 9; ++t) sred[wave][t] = m[t];
    }
    __syncthreads();
#pragma unroll
    for (int t = 0; t < 9; ++t)
        m[t] = (sred[0][t] + sred[1][t] + sred[2][t] + sred[3][t]) * (1.0f / 256.0f);

    float wc[9];
    float asum = 0.0f;
#pragma unroll
    for (int t = 0; t < 9; ++t) {
        float v = w9[t] - m[t];
        v = fminf(fmaxf(v, -1.0f), 1.0f);
        wc[t] = v;
        asum += fabsf(v);
    }
#pragma unroll
    for (int s = 1; s < 64; s <<= 1) asum += __shfl_xor(asum, s, 64);
    __syncthreads();
    if (lane == 0) sred[wave][9] = asum;
    __syncthreads();
    if (i == 0)
        alpha[o] = (sred[0][9] + sred[1][9] + sred[2][9] + sred[3][9]) * (1.0f / 2304.0f);

#pragma unroll
    for (int t = 0; t < 9; ++t) {
        u64 bb = __ballot(wc[t] > 0.0f);   // bit=1 <-> +1
        if (lane == 0) wbits[o * 36 + t * 4 + wave] = bb;
    }
}

// ---------------- conv row processor (lanes = o, uniform window) ----------------
template<int R0, int R1>
__device__ __forceinline__ void run_row(
    const u64* __restrict__ tile,    // [3][56][4]
    const u64 wr[36],                // this lane's weights [tap][j]
    short* __restrict__ srow,        // S + pos_base*256 + o
    int& s_acc, int& q_acc)
{
    constexpr int NR = R1 - R0 + 1;

    // ---- w = 0 : kw in {1,2} ----
    {
        int acc = 0;
#pragma unroll
        for (int kh = R0; kh <= R1; ++kh)
#pragma unroll
            for (int kw = 1; kw <= 2; ++kw)
#pragma unroll
                for (int j = 0; j < 4; ++j)
                    acc += (int)__popcll(tile[(kh * 56 + (kw - 1)) * 4 + j] ^ wr[(kh * 3 + kw) * 4 + j]);
        int S = NR * 2 * 256 - 2 * acc;
        srow[0] = (short)S; s_acc += S; q_acc += S * S;
    }

    // ring: slot(col) = col % 3; preload cols 0,1
    u64 xc[3][3][4];
#pragma unroll
    for (int kh = R0; kh <= R1; ++kh)
#pragma unroll
        for (int j = 0; j < 4; ++j) {
            xc[0][kh][j] = tile[(kh * 56 + 0) * 4 + j];
            xc[1][kh][j] = tile[(kh * 56 + 1) * 4 + j];
        }

    for (int wb = 1; wb <= 52; wb += 3) {
#pragma unroll
        for (int u = 0; u < 3; ++u) {
            const int w = wb + u;                 // 1..54, w % 3 == (1+u) % 3
#pragma unroll
            for (int kh = R0; kh <= R1; ++kh)
#pragma unroll
                for (int j = 0; j < 4; ++j)
                    xc[(u + 2) % 3][kh][j] = tile[(kh * 56 + (w + 1)) * 4 + j];
            int acc = 0;
#pragma unroll
            for (int kh = R0; kh <= R1; ++kh)
#pragma unroll
                for (int kw = 0; kw < 3; ++kw)
#pragma unroll
                    for (int j = 0; j < 4; ++j)
                        acc += (int)__popcll(xc[(u + kw) % 3][kh][j] ^ wr[(kh * 3 + kw) * 4 + j]);
            int S = NR * 3 * 256 - 2 * acc;
            srow[w * 256] = (short)S; s_acc += S; q_acc += S * S;
        }
    }

    // ---- w = 55 : kw in {0,1}; cols 54,55 live in slots 0,1 ----
    {
        int acc = 0;
#pragma unroll
        for (int kh = R0; kh <= R1; ++kh)
#pragma unroll
            for (int kw = 0; kw <= 1; ++kw)
#pragma unroll
                for (int j = 0; j < 4; ++j)
                    acc += (int)__popcll(xc[(54 + kw) % 3][kh][j] ^ wr[(kh * 3 + kw) * 4 + j]);
        int S = NR * 2 * 256 - 2 * acc;
        srow[55 * 256] = (short)S; s_acc += S; q_acc += S * S;
    }
}

// ---------------- Kernel 2: XNOR-popcount conv -> S (NHWC int16) + fused stats ----------------
// launch_bounds(256,2): allow up to 256 VGPRs so weights(72)+ring(72) stay register-resident.
__global__ __launch_bounds__(256, 2) void kc_conv(
    const u64* __restrict__ xbits,
    const u64* __restrict__ wbits,
    short* __restrict__ S,           // [NPOS][256]
    int* __restrict__ ssum,
    unsigned long long* __restrict__ qsum)
{
    const int blk = blockIdx.x;        // (b,h)
    const int b = blk / H_;
    const int h = blk - b * H_;
    const int o = threadIdx.x;         // lane = consecutive o

    __shared__ u64 tile[3 * W_ * 4];   // rows h-1..h+1 (clamped), [r][w][j]
    for (int idx = threadIdx.x; idx < 3 * W_ * 4; idx += 256) {
        int r = idx / (W_ * 4);
        int rem = idx - r * (W_ * 4);
        int hr = min(max(h - 1 + r, 0), H_ - 1);
        tile[idx] = xbits[((size_t)(b * HW + hr * W_)) * 4 + rem];
    }

    // this lane's weights: 36 u64, register-resident
    u64 wr[36];
    const ulonglong2* wp = (const ulonglong2*)(wbits + (size_t)o * 36);
#pragma unroll
    for (int i = 0; i < 18; ++i) { ulonglong2 v = wp[i]; wr[2 * i] = v.x; wr[2 * i + 1] = v.y; }

    __syncthreads();

    short* srow = S + ((size_t)(b * HW + h * W_)) * 256 + o;
    int s_acc = 0, q_acc = 0;
    if (h == 0)        run_row<1, 2>(tile, wr, srow, s_acc, q_acc);
    else if (h == 55)  run_row<0, 1>(tile, wr, srow, s_acc, q_acc);
    else               run_row<0, 2>(tile, wr, srow, s_acc, q_acc);

    atomicAdd(&ssum[o], s_acc);
    atomicAdd(&qsum[o], (unsigned long long)(long long)q_acc);
}

// ---------------- Kernel 3: finalize BN (per-block) + NHWC->NCHW apply + ReLU ----------------
__global__ __launch_bounds__(256) void kb_apply(
    const short* __restrict__ S,
    const int* __restrict__ ssum,
    const unsigned long long* __restrict__ qsum,
    const float* __restrict__ alpha,
    const float* __restrict__ gamma,
    const float* __restrict__ beta,
    float* __restrict__ out)
{
    const int blk = blockIdx.x;        // (b,h)
    const int b = blk / H_;
    const int h = blk - b * H_;
    const int tid = threadIdx.x;

    __shared__ float s_scale[256], s_shift[256];
    __shared__ short lds[W_ * 258];    // [p][c], padded row stride 258 shorts

    {   // per-channel BN finalize (cheap, recomputed per block)
        const int o = tid;
        const double N = (double)NPOS;
        double meanS = (double)ssum[o] / N;
        double varS = (double)qsum[o] / N - meanS * meanS;
        double a = (double)alpha[o];
        double rstd = 1.0 / sqrt(a * a * varS + 1e-5);
        double g = (double)gamma[o];
        s_scale[o] = (float)(g * a * rstd);
        s_shift[o] = (float)((double)beta[o] - g * a * meanS * rstd);
        // conv bias cancels exactly in training-mode BN
    }

    // coalesced copy in: row block is 56*256 shorts contiguous
    const u32* Sw = (const u32*)(S + ((size_t)(b * HW + h * W_)) * 256);
    for (int k = tid; k < W_ * 128; k += 256) {
        int p = k >> 7, cp = k & 127;
        *(u32*)&lds[p * 258 + cp * 2] = Sw[k];
    }
    __syncthreads();

    const int p = tid & 63;            // position within row
    const int cq = tid >> 6;           // channel-pair sub-group
    if (p < W_) {
        const size_t obase = (size_t)b * COUT * HW + (size_t)h * W_ + p;
#pragma unroll 4
        for (int it = 0; it < 32; ++it) {
            const int pr = it * 4 + cq;               // pair index, wave-uniform
            const u32 v = *(const u32*)&lds[p * 258 + pr * 2];
            const int c0 = 2 * pr, c1 = c0 + 1;
            const float f0 = fmaxf(fmaf((float)(short)(v & 0xFFFF), s_scale[c0], s_shift[c0]), 0.0f);
            const float f1 = fmaxf(fmaf((float)(short)(v >> 16),    s_scale[c1], s_shift[c1]), 0.0f);
            out[obase + (size_t)c0 * HW] = f0;
            out[obase + (size_t)c1 * HW] = f1;
        }
    }
}

extern "C" void kernel_launch(void* const* d_in, const int* in_sizes, int n_in,
                              void* d_out, int out_size, void* d_ws, size_t ws_size,
                              hipStream_t stream) {
    const float* x     = (const float*)d_in[0];   // [32,256,56,56]
    const float* wgt   = (const float*)d_in[1];   // [256,256,3,3]
    // d_in[2] = bias: cancels exactly in BN, unused
    const float* gamma = (const float*)d_in[3];
    const float* beta  = (const float*)d_in[4];
    float* out = (float*)d_out;

    char* ws = (char*)d_ws;
    u64*   wbits = (u64*)(ws + 0);
    float* alpha = (float*)(ws + 73728);
    int*   ssum  = (int*)(ws + 74752);
    unsigned long long* qsum = (unsigned long long*)(ws + 75776);
    u64*   xbits = (u64*)(ws + 79872);
    short* Sarr  = (short*)(ws + 3291136);

    k_prep<<<NPACKBLK + 256, 256, 0, stream>>>(x, wgt, xbits, wbits, alpha, ssum, qsum);
    kc_conv<<<NROW, 256, 0, stream>>>(xbits, wbits, Sarr, ssum, qsum);
    kb_apply<<<NROW, 256, 0, stream>>>(Sarr, ssum, qsum, alpha, gamma, beta, out);
}